// Round 7
// baseline (101.929 us; speedup 1.0000x reference)
//
#include <hip/hip_runtime.h>
#include <math.h>

#define G 160
#define GM1 159
#define NS 558
#define CHSTRIDE (160 * 160 * 160)
#define G3 (160 * 160 * 160)

#define DENS_SCALE (10.0f / 255.0f)
#define DENS_BIAS  (-5.0f)
#define COL_SCALE  (7.0f / 255.0f)
#define COL_BIAS   (-3.5f)

#define NBUCKET 512
#define MAXRAYS 16384

// ---------------- fused prep: block 0 sorts rays, others pack grid ----------------

__device__ __forceinline__ unsigned int q8(float v, float bias, float invscale) {
    return (unsigned int)lrintf(fminf(fmaxf((v - bias) * invscale, 0.f), 255.f));
}

__global__ __launch_bounds__(1024) void prep_fused(
    const float* __restrict__ dens,
    const float* __restrict__ k0,
    const float* __restrict__ rays_o,
    const float* __restrict__ rays_d,
    unsigned int* __restrict__ packed,
    unsigned int* __restrict__ order, int N)
{
    __shared__ unsigned short skeys[MAXRAYS];
    __shared__ unsigned int hist[NBUCKET];
    __shared__ unsigned int tmp[NBUCKET];
    __shared__ unsigned int offs[NBUCKET];

    const int tid = threadIdx.x;

    if (blockIdx.x == 0) {
        // ---- single-block counting sort by bbox entry cell (8x8x8) ----
        for (int i = tid; i < NBUCKET; i += 1024) hist[i] = 0;
        __syncthreads();
        for (int r = tid; r < N; r += 1024) {
            const float ox = rays_o[r * 3 + 0], oy = rays_o[r * 3 + 1], oz = rays_o[r * 3 + 2];
            const float dx = rays_d[r * 3 + 0], dy = rays_d[r * 3 + 1], dz = rays_d[r * 3 + 2];
            const float vx = (dx == 0.f) ? 1e-6f : dx;
            const float vy = (dy == 0.f) ? 1e-6f : dy;
            const float vz = (dz == 0.f) ? 1e-6f : dz;
            const float rax = (1.f - ox) / vx, rbx = (-1.f - ox) / vx;
            const float ray_ = (1.f - oy) / vy, rby = (-1.f - oy) / vy;
            const float raz = (1.f - oz) / vz, rbz = (-1.f - oz) / vz;
            float tmin = fmaxf(fmaxf(fminf(rax, rbx), fminf(ray_, rby)), fminf(raz, rbz));
            tmin = fminf(fmaxf(tmin, 0.2f), 6.0f);
            const float px = fminf(fmaxf(fmaf(dx, tmin, ox), -1.f), 1.f);
            const float py = fminf(fmaxf(fmaf(dy, tmin, oy), -1.f), 1.f);
            const float pz = fminf(fmaxf(fmaf(dz, tmin, oz), -1.f), 1.f);
            const int cx = min(7, (int)((px + 1.f) * 4.f));
            const int cy = min(7, (int)((py + 1.f) * 4.f));
            const int cz = min(7, (int)((pz + 1.f) * 4.f));
            const unsigned int key = (unsigned int)((cx << 6) | (cy << 3) | cz);
            skeys[r] = (unsigned short)key;
            atomicAdd(&hist[key], 1u);
        }
        __syncthreads();
        if (tid < NBUCKET) tmp[tid] = hist[tid];
        __syncthreads();
        for (int off = 1; off < NBUCKET; off <<= 1) {
            unsigned int v = 0;
            if (tid < NBUCKET && tid >= off) v = tmp[tid - off];
            __syncthreads();
            if (tid < NBUCKET) tmp[tid] += v;
            __syncthreads();
        }
        if (tid < NBUCKET) offs[tid] = tmp[tid] - hist[tid];
        __syncthreads();
        for (int r = tid; r < N; r += 1024) {
            const unsigned int pos = atomicAdd(&offs[skeys[r]], 1u);
            order[pos] = (unsigned int)r;
        }
    } else {
        // ---- pack 4 voxels/thread: {dens, k0.rgb} -> u8x4 ----
        const int base = ((blockIdx.x - 1) * 1024 + tid) * 4;
        if (base + 3 < G3) {
            const float4 d = *(const float4*)(dens + base);
            const float4 r = *(const float4*)(k0 + base);
            const float4 g = *(const float4*)(k0 + CHSTRIDE + base);
            const float4 b = *(const float4*)(k0 + 2 * CHSTRIDE + base);
            const float dis = 255.f / 10.f, cis = 255.f / 7.f;
            uint4 o;
            o.x = q8(d.x, DENS_BIAS, dis) | (q8(r.x, COL_BIAS, cis) << 8) |
                  (q8(g.x, COL_BIAS, cis) << 16) | (q8(b.x, COL_BIAS, cis) << 24);
            o.y = q8(d.y, DENS_BIAS, dis) | (q8(r.y, COL_BIAS, cis) << 8) |
                  (q8(g.y, COL_BIAS, cis) << 16) | (q8(b.y, COL_BIAS, cis) << 24);
            o.z = q8(d.z, DENS_BIAS, dis) | (q8(r.z, COL_BIAS, cis) << 8) |
                  (q8(g.z, COL_BIAS, cis) << 16) | (q8(b.z, COL_BIAS, cis) << 24);
            o.w = q8(d.w, DENS_BIAS, dis) | (q8(r.w, COL_BIAS, cis) << 8) |
                  (q8(g.w, COL_BIAS, cis) << 16) | (q8(b.w, COL_BIAS, cis) << 24);
            *(uint4*)(packed + base) = o;
        }
    }
}

// ---------------- render: software-pipelined, branchless sampling ----------------

__device__ __forceinline__ float ub(unsigned int q, int c) {
    return (float)((q >> (c * 8)) & 0xffu);   // v_cvt_f32_ubyte{c}
}

struct SampleData {
    unsigned int q000, q001, q010, q011, q100, q101, q110, q111;
    float w000, w001, w010, w011, w100, w101, w110, w111;
    float amask;
};

__device__ __forceinline__ SampleData fetch_sample(
    const unsigned int* __restrict__ pg,
    float ex, float ey, float ez, float gx, float gy, float gz, int s)
{
    SampleData r;
    const float sF = (float)s;
    const float fx = fmaf(gx, sF, ex);
    const float fy = fmaf(gy, sF, ey);
    const float fz = fmaf(gz, sF, ez);
    const bool valid = (fx >= 0.f) && (fx <= 159.f) && (fy >= 0.f) &&
                       (fy <= 159.f) && (fz >= 0.f) && (fz <= 159.f);
    r.amask = valid ? 1.f : 0.f;
    const float cfx = __builtin_amdgcn_fmed3f(fx, 0.f, 159.f);
    const float cfy = __builtin_amdgcn_fmed3f(fy, 0.f, 159.f);
    const float cfz = __builtin_amdgcn_fmed3f(fz, 0.f, 159.f);
    const int x0 = (int)cfx; const float tx = cfx - (float)x0;
    const int y0 = (int)cfy; const float ty = cfy - (float)y0;
    const int z0 = (int)cfz; const float tz = cfz - (float)z0;
    const int x1 = min(x0 + 1, GM1);
    const int y1 = min(y0 + 1, GM1);
    // z1 needs no clamp: when z0==159, tz==0 so the +1 value has zero weight.
    // The 4-byte overrun at the very last voxel lands in order[] (finite data).
    const float mx = 1.f - tx, my = 1.f - ty, mz = 1.f - tz;
    const float w00 = mx * my, w01 = mx * ty, w10 = tx * my, w11 = tx * ty;
    r.w000 = w00 * mz; r.w001 = w00 * tz;
    r.w010 = w01 * mz; r.w011 = w01 * tz;
    r.w100 = w10 * mz; r.w101 = w10 * tz;
    r.w110 = w11 * mz; r.w111 = w11 * tz;
    const int xg0 = x0 * G, xg1 = x1 * G;
    const int i00 = (xg0 + y0) * G + z0;
    const int i01 = (xg0 + y1) * G + z0;
    const int i10 = (xg1 + y0) * G + z0;
    const int i11 = (xg1 + y1) * G + z0;
    r.q000 = pg[i00]; r.q001 = pg[i00 + 1];
    r.q010 = pg[i01]; r.q011 = pg[i01 + 1];
    r.q100 = pg[i10]; r.q101 = pg[i10 + 1];
    r.q110 = pg[i11]; r.q111 = pg[i11 + 1];
    return r;
}

__device__ __forceinline__ void shade(const SampleData& d,
    float& alpha, float& cr, float& cg, float& cb)
{
    const float ACT_SHIFT = -4.59511985013459f;
    float acc[4];
    #pragma unroll
    for (int ch = 0; ch < 4; ++ch) {
        acc[ch] = d.w000 * ub(d.q000, ch) + d.w001 * ub(d.q001, ch) +
                  d.w010 * ub(d.q010, ch) + d.w011 * ub(d.q011, ch) +
                  d.w100 * ub(d.q100, ch) + d.w101 * ub(d.q101, ch) +
                  d.w110 * ub(d.q110, ch) + d.w111 * ub(d.q111, ch);
    }
    const float dens = fmaf(acc[0], DENS_SCALE, DENS_BIAS);
    const float vr   = fmaf(acc[1], COL_SCALE,  COL_BIAS);
    const float vg   = fmaf(acc[2], COL_SCALE,  COL_BIAS);
    const float vb   = fmaf(acc[3], COL_SCALE,  COL_BIAS);
    const float e = __expf(dens + ACT_SHIFT);
    alpha = (1.f - __builtin_amdgcn_rsqf(1.f + e)) * d.amask;
    cr = __builtin_amdgcn_rcpf(1.f + __expf(-vr));
    cg = __builtin_amdgcn_rcpf(1.f + __expf(-vg));
    cb = __builtin_amdgcn_rcpf(1.f + __expf(-vb));
}

__global__ __launch_bounds__(256) void dvgo_render_u8(
    const float* __restrict__ rays_o,
    const float* __restrict__ rays_d,
    const unsigned int* __restrict__ pg,
    const unsigned int* __restrict__ order,   // may be null -> identity
    float* __restrict__ out, int N)
{
    // Identity block->slot mapping: consecutive sorted blocks round-robin
    // across XCDs. Balances ray-length load (sorted chunks correlate with
    // length); all XCDs march the sorted list in sync, sharing hot regions.
    const int slot = (int)(blockIdx.x * 4 + (threadIdx.x >> 6));
    const int lane = (int)(threadIdx.x & 63u);
    if (slot >= N) return;
    const int wave = order ? (int)order[slot] : slot;

    const float ox = rays_o[wave * 3 + 0], oy = rays_o[wave * 3 + 1], oz = rays_o[wave * 3 + 2];
    const float dx = rays_d[wave * 3 + 0], dy = rays_d[wave * 3 + 1], dz = rays_d[wave * 3 + 2];
    const float inv_norm = __builtin_amdgcn_rsqf(dx * dx + dy * dy + dz * dz);

    const float vx = (dx == 0.f) ? 1e-6f : dx;
    const float vy = (dy == 0.f) ? 1e-6f : dy;
    const float vz = (dz == 0.f) ? 1e-6f : dz;
    const float rax = (1.f - ox) / vx, rbx = (-1.f - ox) / vx;
    const float ray_ = (1.f - oy) / vy, rby = (-1.f - oy) / vy;
    const float raz = (1.f - oz) / vz, rbz = (-1.f - oz) / vz;
    float tmin = fmaxf(fmaxf(fminf(rax, rbx), fminf(ray_, rby)), fminf(raz, rbz));
    float tmax = fminf(fminf(fmaxf(rax, rbx), fmaxf(ray_, rby)), fmaxf(raz, rbz));
    tmin = fminf(fmaxf(tmin, 0.2f), 6.0f);
    tmax = fminf(fmaxf(tmax, 0.2f), 6.0f);

    const float dt = 0.00625f * inv_norm;

    // ray fused into index space: f = fmaf(g, s, e)
    const float ex = (fmaf(dx, tmin, ox) + 1.f) * 79.5f;
    const float ey = (fmaf(dy, tmin, oy) + 1.f) * 79.5f;
    const float ez = (fmaf(dz, tmin, oz) + 1.f) * 79.5f;
    const float gx = dx * dt * 79.5f;
    const float gy = dy * dt * 79.5f;
    const float gz = dz * dt * 79.5f;

    int n_samp = 0;
    if (!(tmax < tmin)) n_samp = min(NS, (int)((tmax - tmin) / dt) + 2);
    const int n_chunks = (n_samp + 63) >> 6;

    float T = 1.f;
    float ar = 0.f, ag = 0.f, ab = 0.f;

    if (n_chunks > 0) {
        SampleData cur = fetch_sample(pg, ex, ey, ez, gx, gy, gz, lane);
        for (int c = 0; c < n_chunks; ++c) {
            SampleData nxt;
            const bool more = (c + 1 < n_chunks);          // wave-uniform
            if (more) nxt = fetch_sample(pg, ex, ey, ez, gx, gy, gz, ((c + 1) << 6) + lane);

            float alpha, cr, cg, cb;
            shade(cur, alpha, cr, cg, cb);

            // inclusive prefix product of (1-alpha) across the wave
            float incl = 1.f - alpha;
            #pragma unroll
            for (int off = 1; off < 64; off <<= 1) {
                const float v = __shfl_up(incl, off, 64);
                if (lane >= off) incl *= v;
            }
            float excl = __shfl_up(incl, 1, 64);
            if (lane == 0) excl = 1.f;

            const float w = alpha * T * excl;
            ar = fmaf(w, cr, ar);
            ag = fmaf(w, cg, ag);
            ab = fmaf(w, cb, ab);
            T *= __shfl(incl, 63, 64);

            cur = nxt;
        }
    }

    #pragma unroll
    for (int off = 32; off > 0; off >>= 1) {
        ar += __shfl_down(ar, off, 64);
        ag += __shfl_down(ag, off, 64);
        ab += __shfl_down(ab, off, 64);
    }
    if (lane == 0) {
        out[wave * 3 + 0] = ar + T;
        out[wave * 3 + 1] = ag + T;
        out[wave * 3 + 2] = ab + T;
    }
}

// ---------------- fallback: f32 4-array render (ws too small) ----------------

__global__ __launch_bounds__(256) void dvgo_render_f32(
    const float* __restrict__ rays_o,
    const float* __restrict__ rays_d,
    const float* __restrict__ dens_g,
    const float* __restrict__ k0_g,
    float* __restrict__ out, int N)
{
    const int wave = (int)((blockIdx.x * 256u + threadIdx.x) >> 6);
    const int lane = (int)(threadIdx.x & 63u);
    if (wave >= N) return;

    const float ox = rays_o[wave * 3 + 0], oy = rays_o[wave * 3 + 1], oz = rays_o[wave * 3 + 2];
    const float dx = rays_d[wave * 3 + 0], dy = rays_d[wave * 3 + 1], dz = rays_d[wave * 3 + 2];
    const float inv_norm = rsqrtf(dx * dx + dy * dy + dz * dz);

    const float vx = (dx == 0.f) ? 1e-6f : dx;
    const float vy = (dy == 0.f) ? 1e-6f : dy;
    const float vz = (dz == 0.f) ? 1e-6f : dz;
    const float rax = (1.f - ox) / vx, rbx = (-1.f - ox) / vx;
    const float ray_ = (1.f - oy) / vy, rby = (-1.f - oy) / vy;
    const float raz = (1.f - oz) / vz, rbz = (-1.f - oz) / vz;
    float tmin = fmaxf(fmaxf(fminf(rax, rbx), fminf(ray_, rby)), fminf(raz, rbz));
    float tmax = fminf(fminf(fmaxf(rax, rbx), fmaxf(ray_, rby)), fmaxf(raz, rbz));
    tmin = fminf(fmaxf(tmin, 0.2f), 6.0f);
    tmax = fminf(fmaxf(tmax, 0.2f), 6.0f);
    const bool ray_oob = (tmax < tmin);

    const float dt = 0.00625f * inv_norm;
    const float ACT_SHIFT = -4.59511985013459f;

    float T = 1.f;
    float ar = 0.f, ag = 0.f, ab = 0.f;

    for (int s0 = 0; s0 < NS; s0 += 64) {
        const int s = s0 + lane;
        float alpha = 0.f, cr = 0.f, cg = 0.f, cb = 0.f;
        bool valid = false;
        if (!ray_oob && s < NS) {
            const float t = tmin + dt * (float)s;
            const float px = fmaf(dx, t, ox);
            const float py = fmaf(dy, t, oy);
            const float pz = fmaf(dz, t, oz);
            if (px >= -1.f && px <= 1.f && py >= -1.f && py <= 1.f &&
                pz >= -1.f && pz <= 1.f) {
                valid = true;
                const float fx = (px + 1.f) * 79.5f;
                const float fy = (py + 1.f) * 79.5f;
                const float fz = (pz + 1.f) * 79.5f;
                int x0 = (int)fx; const float tx = fx - (float)x0;
                int y0 = (int)fy; const float ty = fy - (float)y0;
                int z0 = (int)fz; const float tz = fz - (float)z0;
                x0 = min(x0, GM1); y0 = min(y0, GM1); z0 = min(z0, GM1);
                const int x1 = min(x0 + 1, GM1);
                const int y1 = min(y0 + 1, GM1);
                const int z1 = min(z0 + 1, GM1);

                const float mx = 1.f - tx, my = 1.f - ty, mz = 1.f - tz;
                const float w00 = mx * my, w01 = mx * ty, w10 = tx * my, w11 = tx * ty;
                const float w000 = w00 * mz, w001 = w00 * tz;
                const float w010 = w01 * mz, w011 = w01 * tz;
                const float w100 = w10 * mz, w101 = w10 * tz;
                const float w110 = w11 * mz, w111 = w11 * tz;

                const int b00 = (x0 * G + y0) * G;
                const int b01 = (x0 * G + y1) * G;
                const int b10 = (x1 * G + y0) * G;
                const int b11 = (x1 * G + y1) * G;

                const float dens =
                    w000 * dens_g[b00 + z0] + w001 * dens_g[b00 + z1] +
                    w010 * dens_g[b01 + z0] + w011 * dens_g[b01 + z1] +
                    w100 * dens_g[b10 + z0] + w101 * dens_g[b10 + z1] +
                    w110 * dens_g[b11 + z0] + w111 * dens_g[b11 + z1];

                const float e = __expf(dens + ACT_SHIFT);
                alpha = 1.f - rsqrtf(1.f + e);

                #pragma unroll
                for (int ch = 0; ch < 3; ++ch) {
                    const float* k0c = k0_g + ch * CHSTRIDE;
                    const float v =
                        w000 * k0c[b00 + z0] + w001 * k0c[b00 + z1] +
                        w010 * k0c[b01 + z0] + w011 * k0c[b01 + z1] +
                        w100 * k0c[b10 + z0] + w101 * k0c[b10 + z1] +
                        w110 * k0c[b11 + z0] + w111 * k0c[b11 + z1];
                    const float sg = 1.f / (1.f + __expf(-v));
                    if (ch == 0) cr = sg; else if (ch == 1) cg = sg; else cb = sg;
                }
            }
        }

        float incl = 1.f - alpha;
        #pragma unroll
        for (int off = 1; off < 64; off <<= 1) {
            const float v = __shfl_up(incl, off, 64);
            if (lane >= off) incl *= v;
        }
        float excl = __shfl_up(incl, 1, 64);
        if (lane == 0) excl = 1.f;

        const float w = alpha * T * excl;
        ar = fmaf(w, cr, ar);
        ag = fmaf(w, cg, ag);
        ab = fmaf(w, cb, ab);

        T *= __shfl(incl, 63, 64);

        if (__ballot(valid) == 0ull) break;
        if (T < 1e-5f) break;
    }

    #pragma unroll
    for (int off = 32; off > 0; off >>= 1) {
        ar += __shfl_down(ar, off, 64);
        ag += __shfl_down(ag, off, 64);
        ab += __shfl_down(ab, off, 64);
    }
    if (lane == 0) {
        out[wave * 3 + 0] = ar + T;
        out[wave * 3 + 1] = ag + T;
        out[wave * 3 + 2] = ab + T;
    }
}

extern "C" void kernel_launch(void* const* d_in, const int* in_sizes, int n_in,
                              void* d_out, int out_size, void* d_ws, size_t ws_size,
                              hipStream_t stream) {
    const float* rays_o  = (const float*)d_in[0];
    const float* rays_d  = (const float*)d_in[1];
    const float* density = (const float*)d_in[2];
    const float* k0      = (const float*)d_in[3];
    float* out = (float*)d_out;
    const int N = in_sizes[0] / 3;

    const int blocks = (N * 64 + 255) / 256;

    // ws layout: packed grid | order[N]  (order doubles as overrun pad for z-pair loads)
    const size_t grid_b  = (size_t)G3 * 4;
    const size_t need = grid_b + (size_t)N * 4;

    if (ws_size >= need && N <= MAXRAYS) {
        unsigned int* packed = (unsigned int*)d_ws;
        unsigned int* order  = (unsigned int*)((char*)d_ws + grid_b);
        const int pack_blocks = (G3 + 4095) / 4096;   // 1000
        prep_fused<<<pack_blocks + 1, 1024, 0, stream>>>(density, k0, rays_o, rays_d,
                                                         packed, order, N);
        dvgo_render_u8<<<blocks, 256, 0, stream>>>(rays_o, rays_d, packed, order, out, N);
    } else {
        dvgo_render_f32<<<blocks, 256, 0, stream>>>(rays_o, rays_d, density, k0, out, N);
    }
}

// Round 8
// 87.445 us; speedup vs baseline: 1.1656x; 1.1656x over previous
//
#include <hip/hip_runtime.h>
#include <math.h>

#define G 160
#define GM1 159
#define NS 558
#define CHSTRIDE (160 * 160 * 160)
#define G3 (160 * 160 * 160)

#define DENS_SCALE (10.0f / 255.0f)
#define DENS_BIAS  (-5.0f)
#define COL_SCALE  (7.0f / 255.0f)
#define COL_BIAS   (-3.5f)

#define NBUCKET 512
#define MAXRAYS 16384

// ---------------- fused prep: block 0 sorts rays, others pack grid ----------------

__device__ __forceinline__ unsigned int q8(float v, float bias, float invscale) {
    return (unsigned int)lrintf(fminf(fmaxf((v - bias) * invscale, 0.f), 255.f));
}

__global__ __launch_bounds__(1024) void prep_fused(
    const float* __restrict__ dens,
    const float* __restrict__ k0,
    const float* __restrict__ rays_o,
    const float* __restrict__ rays_d,
    unsigned int* __restrict__ packed,
    unsigned int* __restrict__ order, int N)
{
    __shared__ unsigned short skeys[MAXRAYS];
    __shared__ unsigned int hist[NBUCKET];
    __shared__ unsigned int tmp[NBUCKET];
    __shared__ unsigned int offs[NBUCKET];

    const int tid = threadIdx.x;

    if (blockIdx.x == 0) {
        // ---- single-block counting sort by bbox entry cell (8x8x8) ----
        for (int i = tid; i < NBUCKET; i += 1024) hist[i] = 0;
        __syncthreads();
        for (int r = tid; r < N; r += 1024) {
            const float ox = rays_o[r * 3 + 0], oy = rays_o[r * 3 + 1], oz = rays_o[r * 3 + 2];
            const float dx = rays_d[r * 3 + 0], dy = rays_d[r * 3 + 1], dz = rays_d[r * 3 + 2];
            const float vx = (dx == 0.f) ? 1e-6f : dx;
            const float vy = (dy == 0.f) ? 1e-6f : dy;
            const float vz = (dz == 0.f) ? 1e-6f : dz;
            const float rax = (1.f - ox) / vx, rbx = (-1.f - ox) / vx;
            const float ray_ = (1.f - oy) / vy, rby = (-1.f - oy) / vy;
            const float raz = (1.f - oz) / vz, rbz = (-1.f - oz) / vz;
            float tmin = fmaxf(fmaxf(fminf(rax, rbx), fminf(ray_, rby)), fminf(raz, rbz));
            tmin = fminf(fmaxf(tmin, 0.2f), 6.0f);
            const float px = fminf(fmaxf(fmaf(dx, tmin, ox), -1.f), 1.f);
            const float py = fminf(fmaxf(fmaf(dy, tmin, oy), -1.f), 1.f);
            const float pz = fminf(fmaxf(fmaf(dz, tmin, oz), -1.f), 1.f);
            const int cx = min(7, (int)((px + 1.f) * 4.f));
            const int cy = min(7, (int)((py + 1.f) * 4.f));
            const int cz = min(7, (int)((pz + 1.f) * 4.f));
            const unsigned int key = (unsigned int)((cx << 6) | (cy << 3) | cz);
            skeys[r] = (unsigned short)key;
            atomicAdd(&hist[key], 1u);
        }
        __syncthreads();
        if (tid < NBUCKET) tmp[tid] = hist[tid];
        __syncthreads();
        for (int off = 1; off < NBUCKET; off <<= 1) {
            unsigned int v = 0;
            if (tid < NBUCKET && tid >= off) v = tmp[tid - off];
            __syncthreads();
            if (tid < NBUCKET) tmp[tid] += v;
            __syncthreads();
        }
        if (tid < NBUCKET) offs[tid] = tmp[tid] - hist[tid];
        __syncthreads();
        for (int r = tid; r < N; r += 1024) {
            const unsigned int pos = atomicAdd(&offs[skeys[r]], 1u);
            order[pos] = (unsigned int)r;
        }
    } else {
        // ---- pack 4 voxels/thread: {dens, k0.rgb} -> u8x4 ----
        const int base = ((blockIdx.x - 1) * 1024 + tid) * 4;
        if (base + 3 < G3) {
            const float4 d = *(const float4*)(dens + base);
            const float4 r = *(const float4*)(k0 + base);
            const float4 g = *(const float4*)(k0 + CHSTRIDE + base);
            const float4 b = *(const float4*)(k0 + 2 * CHSTRIDE + base);
            const float dis = 255.f / 10.f, cis = 255.f / 7.f;
            uint4 o;
            o.x = q8(d.x, DENS_BIAS, dis) | (q8(r.x, COL_BIAS, cis) << 8) |
                  (q8(g.x, COL_BIAS, cis) << 16) | (q8(b.x, COL_BIAS, cis) << 24);
            o.y = q8(d.y, DENS_BIAS, dis) | (q8(r.y, COL_BIAS, cis) << 8) |
                  (q8(g.y, COL_BIAS, cis) << 16) | (q8(b.y, COL_BIAS, cis) << 24);
            o.z = q8(d.z, DENS_BIAS, dis) | (q8(r.z, COL_BIAS, cis) << 8) |
                  (q8(g.z, COL_BIAS, cis) << 16) | (q8(b.z, COL_BIAS, cis) << 24);
            o.w = q8(d.w, DENS_BIAS, dis) | (q8(r.w, COL_BIAS, cis) << 8) |
                  (q8(g.w, COL_BIAS, cis) << 16) | (q8(b.w, COL_BIAS, cis) << 24);
            *(uint4*)(packed + base) = o;
        }
    }
}

// ---------------- render: 2-deep pipelined, branchless sampling ----------------

__device__ __forceinline__ float ub(unsigned int q, int c) {
    return (float)((q >> (c * 8)) & 0xffu);   // v_cvt_f32_ubyte{c}
}

struct SampleData {
    unsigned int q000, q001, q010, q011, q100, q101, q110, q111;
    float w000, w001, w010, w011, w100, w101, w110, w111;
    float amask;
};

__device__ __forceinline__ SampleData fetch_sample(
    const unsigned int* __restrict__ pg,
    float ex, float ey, float ez, float gx, float gy, float gz, int s)
{
    SampleData r;
    const float sF = (float)s;
    const float fx = fmaf(gx, sF, ex);
    const float fy = fmaf(gy, sF, ey);
    const float fz = fmaf(gz, sF, ez);
    const bool valid = (fx >= 0.f) && (fx <= 159.f) && (fy >= 0.f) &&
                       (fy <= 159.f) && (fz >= 0.f) && (fz <= 159.f);
    r.amask = valid ? 1.f : 0.f;
    const float cfx = __builtin_amdgcn_fmed3f(fx, 0.f, 159.f);
    const float cfy = __builtin_amdgcn_fmed3f(fy, 0.f, 159.f);
    const float cfz = __builtin_amdgcn_fmed3f(fz, 0.f, 159.f);
    const int x0 = (int)cfx; const float tx = cfx - (float)x0;
    const int y0 = (int)cfy; const float ty = cfy - (float)y0;
    const int z0 = (int)cfz; const float tz = cfz - (float)z0;
    const int x1 = min(x0 + 1, GM1);
    const int y1 = min(y0 + 1, GM1);
    // z1 needs no clamp: when z0==159, tz==0 so the +1 value has zero weight.
    // The 4-byte overrun at the very last voxel lands in order[] (finite data).
    const float mx = 1.f - tx, my = 1.f - ty, mz = 1.f - tz;
    const float w00 = mx * my, w01 = mx * ty, w10 = tx * my, w11 = tx * ty;
    r.w000 = w00 * mz; r.w001 = w00 * tz;
    r.w010 = w01 * mz; r.w011 = w01 * tz;
    r.w100 = w10 * mz; r.w101 = w10 * tz;
    r.w110 = w11 * mz; r.w111 = w11 * tz;
    const int xg0 = x0 * G, xg1 = x1 * G;
    const int i00 = (xg0 + y0) * G + z0;
    const int i01 = (xg0 + y1) * G + z0;
    const int i10 = (xg1 + y0) * G + z0;
    const int i11 = (xg1 + y1) * G + z0;
    r.q000 = pg[i00]; r.q001 = pg[i00 + 1];
    r.q010 = pg[i01]; r.q011 = pg[i01 + 1];
    r.q100 = pg[i10]; r.q101 = pg[i10 + 1];
    r.q110 = pg[i11]; r.q111 = pg[i11 + 1];
    return r;
}

__device__ __forceinline__ void shade(const SampleData& d,
    float& alpha, float& cr, float& cg, float& cb)
{
    const float ACT_SHIFT = -4.59511985013459f;
    float acc[4];
    #pragma unroll
    for (int ch = 0; ch < 4; ++ch) {
        acc[ch] = d.w000 * ub(d.q000, ch) + d.w001 * ub(d.q001, ch) +
                  d.w010 * ub(d.q010, ch) + d.w011 * ub(d.q011, ch) +
                  d.w100 * ub(d.q100, ch) + d.w101 * ub(d.q101, ch) +
                  d.w110 * ub(d.q110, ch) + d.w111 * ub(d.q111, ch);
    }
    const float dens = fmaf(acc[0], DENS_SCALE, DENS_BIAS);
    const float vr   = fmaf(acc[1], COL_SCALE,  COL_BIAS);
    const float vg   = fmaf(acc[2], COL_SCALE,  COL_BIAS);
    const float vb   = fmaf(acc[3], COL_SCALE,  COL_BIAS);
    const float e = __expf(dens + ACT_SHIFT);
    alpha = (1.f - __builtin_amdgcn_rsqf(1.f + e)) * d.amask;
    cr = __builtin_amdgcn_rcpf(1.f + __expf(-vr));
    cg = __builtin_amdgcn_rcpf(1.f + __expf(-vg));
    cb = __builtin_amdgcn_rcpf(1.f + __expf(-vb));
}

__global__ __launch_bounds__(256) void dvgo_render_u8(
    const float* __restrict__ rays_o,
    const float* __restrict__ rays_d,
    const unsigned int* __restrict__ pg,
    const unsigned int* __restrict__ order,   // may be null -> identity
    float* __restrict__ out, int N)
{
    // XCD swizzle, 64-block (256-ray) chunks: XCD k processes chunks
    // {k, k+8, k+16, ...} of the sorted ray list -> per-XCD L2 locality
    // windows (proven -34% FETCH vs none) + length balance across XCDs
    // (each XCD samples the whole sorted spectrum).
    unsigned int bid = blockIdx.x;
    const unsigned int nblk = gridDim.x;
    if ((nblk & 511u) == 0u) {
        const unsigned int xcd  = bid & 7u;
        const unsigned int step = bid >> 3;          // sequence within XCD
        const unsigned int cseq = step >> 6;         // which chunk round
        const unsigned int pos  = step & 63u;        // block within chunk
        bid = (cseq * 8u + xcd) * 64u + pos;
    } else if ((nblk & 7u) == 0u) {
        bid = (bid & 7u) * (nblk >> 3) + (bid >> 3);
    }
    const int slot = (int)(bid * 4 + (threadIdx.x >> 6));
    const int lane = (int)(threadIdx.x & 63u);
    if (slot >= N) return;
    const int wave = order ? (int)order[slot] : slot;

    const float ox = rays_o[wave * 3 + 0], oy = rays_o[wave * 3 + 1], oz = rays_o[wave * 3 + 2];
    const float dx = rays_d[wave * 3 + 0], dy = rays_d[wave * 3 + 1], dz = rays_d[wave * 3 + 2];
    const float inv_norm = __builtin_amdgcn_rsqf(dx * dx + dy * dy + dz * dz);

    const float vx = (dx == 0.f) ? 1e-6f : dx;
    const float vy = (dy == 0.f) ? 1e-6f : dy;
    const float vz = (dz == 0.f) ? 1e-6f : dz;
    const float rax = (1.f - ox) / vx, rbx = (-1.f - ox) / vx;
    const float ray_ = (1.f - oy) / vy, rby = (-1.f - oy) / vy;
    const float raz = (1.f - oz) / vz, rbz = (-1.f - oz) / vz;
    float tmin = fmaxf(fmaxf(fminf(rax, rbx), fminf(ray_, rby)), fminf(raz, rbz));
    float tmax = fminf(fminf(fmaxf(rax, rbx), fmaxf(ray_, rby)), fmaxf(raz, rbz));
    tmin = fminf(fmaxf(tmin, 0.2f), 6.0f);
    tmax = fminf(fmaxf(tmax, 0.2f), 6.0f);

    const float dt = 0.00625f * inv_norm;

    // ray fused into index space: f = fmaf(g, s, e)
    const float ex = (fmaf(dx, tmin, ox) + 1.f) * 79.5f;
    const float ey = (fmaf(dy, tmin, oy) + 1.f) * 79.5f;
    const float ez = (fmaf(dz, tmin, oz) + 1.f) * 79.5f;
    const float gx = dx * dt * 79.5f;
    const float gy = dy * dt * 79.5f;
    const float gz = dz * dt * 79.5f;

    int n_samp = 0;
    if (!(tmax < tmin)) n_samp = min(NS, (int)((tmax - tmin) / dt) + 2);
    const int n_chunks = (n_samp + 63) >> 6;

    float T = 1.f;
    float ar = 0.f, ag = 0.f, ab = 0.f;

    if (n_chunks > 0) {
        // 2-deep software pipeline: chunks c+1 and c+2 in flight while shading c.
        SampleData sd0 = fetch_sample(pg, ex, ey, ez, gx, gy, gz, lane);
        SampleData sd1;
        if (n_chunks > 1) sd1 = fetch_sample(pg, ex, ey, ez, gx, gy, gz, 64 + lane);
        for (int c = 0; c < n_chunks; ++c) {
            SampleData sd2;
            if (c + 2 < n_chunks)
                sd2 = fetch_sample(pg, ex, ey, ez, gx, gy, gz, ((c + 2) << 6) + lane);

            float alpha, cr, cg, cb;
            shade(sd0, alpha, cr, cg, cb);

            // inclusive prefix product of (1-alpha) across the wave
            float incl = 1.f - alpha;
            #pragma unroll
            for (int off = 1; off < 64; off <<= 1) {
                const float v = __shfl_up(incl, off, 64);
                if (lane >= off) incl *= v;
            }
            float excl = __shfl_up(incl, 1, 64);
            if (lane == 0) excl = 1.f;

            const float w = alpha * T * excl;
            ar = fmaf(w, cr, ar);
            ag = fmaf(w, cg, ag);
            ab = fmaf(w, cb, ab);
            T *= __shfl(incl, 63, 64);

            sd0 = sd1;
            sd1 = sd2;
        }
    }

    #pragma unroll
    for (int off = 32; off > 0; off >>= 1) {
        ar += __shfl_down(ar, off, 64);
        ag += __shfl_down(ag, off, 64);
        ab += __shfl_down(ab, off, 64);
    }
    if (lane == 0) {
        out[wave * 3 + 0] = ar + T;
        out[wave * 3 + 1] = ag + T;
        out[wave * 3 + 2] = ab + T;
    }
}

// ---------------- fallback: f32 4-array render (ws too small) ----------------

__global__ __launch_bounds__(256) void dvgo_render_f32(
    const float* __restrict__ rays_o,
    const float* __restrict__ rays_d,
    const float* __restrict__ dens_g,
    const float* __restrict__ k0_g,
    float* __restrict__ out, int N)
{
    const int wave = (int)((blockIdx.x * 256u + threadIdx.x) >> 6);
    const int lane = (int)(threadIdx.x & 63u);
    if (wave >= N) return;

    const float ox = rays_o[wave * 3 + 0], oy = rays_o[wave * 3 + 1], oz = rays_o[wave * 3 + 2];
    const float dx = rays_d[wave * 3 + 0], dy = rays_d[wave * 3 + 1], dz = rays_d[wave * 3 + 2];
    const float inv_norm = rsqrtf(dx * dx + dy * dy + dz * dz);

    const float vx = (dx == 0.f) ? 1e-6f : dx;
    const float vy = (dy == 0.f) ? 1e-6f : dy;
    const float vz = (dz == 0.f) ? 1e-6f : dz;
    const float rax = (1.f - ox) / vx, rbx = (-1.f - ox) / vx;
    const float ray_ = (1.f - oy) / vy, rby = (-1.f - oy) / vy;
    const float raz = (1.f - oz) / vz, rbz = (-1.f - oz) / vz;
    float tmin = fmaxf(fmaxf(fminf(rax, rbx), fminf(ray_, rby)), fminf(raz, rbz));
    float tmax = fminf(fminf(fmaxf(rax, rbx), fmaxf(ray_, rby)), fmaxf(raz, rbz));
    tmin = fminf(fmaxf(tmin, 0.2f), 6.0f);
    tmax = fminf(fmaxf(tmax, 0.2f), 6.0f);
    const bool ray_oob = (tmax < tmin);

    const float dt = 0.00625f * inv_norm;
    const float ACT_SHIFT = -4.59511985013459f;

    float T = 1.f;
    float ar = 0.f, ag = 0.f, ab = 0.f;

    for (int s0 = 0; s0 < NS; s0 += 64) {
        const int s = s0 + lane;
        float alpha = 0.f, cr = 0.f, cg = 0.f, cb = 0.f;
        bool valid = false;
        if (!ray_oob && s < NS) {
            const float t = tmin + dt * (float)s;
            const float px = fmaf(dx, t, ox);
            const float py = fmaf(dy, t, oy);
            const float pz = fmaf(dz, t, oz);
            if (px >= -1.f && px <= 1.f && py >= -1.f && py <= 1.f &&
                pz >= -1.f && pz <= 1.f) {
                valid = true;
                const float fx = (px + 1.f) * 79.5f;
                const float fy = (py + 1.f) * 79.5f;
                const float fz = (pz + 1.f) * 79.5f;
                int x0 = (int)fx; const float tx = fx - (float)x0;
                int y0 = (int)fy; const float ty = fy - (float)y0;
                int z0 = (int)fz; const float tz = fz - (float)z0;
                x0 = min(x0, GM1); y0 = min(y0, GM1); z0 = min(z0, GM1);
                const int x1 = min(x0 + 1, GM1);
                const int y1 = min(y0 + 1, GM1);
                const int z1 = min(z0 + 1, GM1);

                const float mx = 1.f - tx, my = 1.f - ty, mz = 1.f - tz;
                const float w00 = mx * my, w01 = mx * ty, w10 = tx * my, w11 = tx * ty;
                const float w000 = w00 * mz, w001 = w00 * tz;
                const float w010 = w01 * mz, w011 = w01 * tz;
                const float w100 = w10 * mz, w101 = w10 * tz;
                const float w110 = w11 * mz, w111 = w11 * tz;

                const int b00 = (x0 * G + y0) * G;
                const int b01 = (x0 * G + y1) * G;
                const int b10 = (x1 * G + y0) * G;
                const int b11 = (x1 * G + y1) * G;

                const float dens =
                    w000 * dens_g[b00 + z0] + w001 * dens_g[b00 + z1] +
                    w010 * dens_g[b01 + z0] + w011 * dens_g[b01 + z1] +
                    w100 * dens_g[b10 + z0] + w101 * dens_g[b10 + z1] +
                    w110 * dens_g[b11 + z0] + w111 * dens_g[b11 + z1];

                const float e = __expf(dens + ACT_SHIFT);
                alpha = 1.f - rsqrtf(1.f + e);

                #pragma unroll
                for (int ch = 0; ch < 3; ++ch) {
                    const float* k0c = k0_g + ch * CHSTRIDE;
                    const float v =
                        w000 * k0c[b00 + z0] + w001 * k0c[b00 + z1] +
                        w010 * k0c[b01 + z0] + w011 * k0c[b01 + z1] +
                        w100 * k0c[b10 + z0] + w101 * k0c[b10 + z1] +
                        w110 * k0c[b11 + z0] + w111 * k0c[b11 + z1];
                    const float sg = 1.f / (1.f + __expf(-v));
                    if (ch == 0) cr = sg; else if (ch == 1) cg = sg; else cb = sg;
                }
            }
        }

        float incl = 1.f - alpha;
        #pragma unroll
        for (int off = 1; off < 64; off <<= 1) {
            const float v = __shfl_up(incl, off, 64);
            if (lane >= off) incl *= v;
        }
        float excl = __shfl_up(incl, 1, 64);
        if (lane == 0) excl = 1.f;

        const float w = alpha * T * excl;
        ar = fmaf(w, cr, ar);
        ag = fmaf(w, cg, ag);
        ab = fmaf(w, cb, ab);

        T *= __shfl(incl, 63, 64);

        if (__ballot(valid) == 0ull) break;
        if (T < 1e-5f) break;
    }

    #pragma unroll
    for (int off = 32; off > 0; off >>= 1) {
        ar += __shfl_down(ar, off, 64);
        ag += __shfl_down(ag, off, 64);
        ab += __shfl_down(ab, off, 64);
    }
    if (lane == 0) {
        out[wave * 3 + 0] = ar + T;
        out[wave * 3 + 1] = ag + T;
        out[wave * 3 + 2] = ab + T;
    }
}

extern "C" void kernel_launch(void* const* d_in, const int* in_sizes, int n_in,
                              void* d_out, int out_size, void* d_ws, size_t ws_size,
                              hipStream_t stream) {
    const float* rays_o  = (const float*)d_in[0];
    const float* rays_d  = (const float*)d_in[1];
    const float* density = (const float*)d_in[2];
    const float* k0      = (const float*)d_in[3];
    float* out = (float*)d_out;
    const int N = in_sizes[0] / 3;

    const int blocks = (N * 64 + 255) / 256;

    // ws layout: packed grid | order[N]  (order doubles as overrun pad for z-pair loads)
    const size_t grid_b  = (size_t)G3 * 4;
    const size_t need = grid_b + (size_t)N * 4;

    if (ws_size >= need && N <= MAXRAYS) {
        unsigned int* packed = (unsigned int*)d_ws;
        unsigned int* order  = (unsigned int*)((char*)d_ws + grid_b);
        const int pack_blocks = (G3 + 4095) / 4096;   // 1000
        prep_fused<<<pack_blocks + 1, 1024, 0, stream>>>(density, k0, rays_o, rays_d,
                                                         packed, order, N);
        dvgo_render_u8<<<blocks, 256, 0, stream>>>(rays_o, rays_d, packed, order, out, N);
    } else {
        dvgo_render_f32<<<blocks, 256, 0, stream>>>(rays_o, rays_d, density, k0, out, N);
    }
}